// Round 20
// baseline (253.012 us; speedup 1.0000x reference)
//
#include <hip/hip_runtime.h>
#include <hip/hip_bf16.h>

typedef __attribute__((ext_vector_type(4))) float f4;
typedef __attribute__((ext_vector_type(8))) short s8;
typedef __attribute__((ext_vector_type(4))) short s4;

__device__ __forceinline__ short f2bf(float f){
  __hip_bfloat16 h = __float2bfloat16(f);
  return __builtin_bit_cast(short, h);
}
__device__ __forceinline__ float bf2f(short h){
  unsigned u = ((unsigned)(unsigned short)h) << 16;
  return __builtin_bit_cast(float, u);
}
__device__ __forceinline__ f4 mfma16(s8 a, s8 b, f4 c){
  return __builtin_amdgcn_mfma_f32_16x16x32_bf16(a, b, c, 0, 0, 0);
}
__device__ __forceinline__ s8 cfrag(const float* p){
  f4 a = *(const f4*)p; f4 b = *(const f4*)(p + 4);
  s8 t = {f2bf(a[0]), f2bf(a[1]), f2bf(a[2]), f2bf(a[3]),
          f2bf(b[0]), f2bf(b[1]), f2bf(b[2]), f2bf(b[3])};
  return t;
}
__device__ __forceinline__ s8 nfrag(const float* p){
  f4 a = *(const f4*)p; f4 b = *(const f4*)(p + 4);
  float ss = a[0]*a[0]+a[1]*a[1]+a[2]*a[2]+a[3]*a[3]
           + b[0]*b[0]+b[1]*b[1]+b[2]*b[2]+b[3]*b[3];
  ss += __shfl_xor(ss, 16); ss += __shfl_xor(ss, 32);
  float f = 1.0f / fmaxf(sqrtf(ss), 1e-12f);
  s8 t = {f2bf(a[0]*f), f2bf(a[1]*f), f2bf(a[2]*f), f2bf(a[3]*f),
          f2bf(b[0]*f), f2bf(b[1]*f), f2bf(b[2]*f), f2bf(b[3]*f)};
  return t;
}
#define SWZ(row) ((((row) ^ ((row) >> 3)) & 7) << 3)

// ---------------------------------------------------------------- k_prep
// blocks 0..287: weight f32->bf16 conversion.
// blocks 288..295: CPB MLP table (tbg[900]) — 32 rows/block, 8 thr/row.
__global__ __launch_bounds__(256) void k_prep(
    const float* __restrict__ vw, const float* __restrict__ ow,
    const float* __restrict__ iw, const float* __restrict__ fw,
    const float* __restrict__ dw, const float* __restrict__ tbl,
    const float* __restrict__ c0b, const float* __restrict__ c0w,
    const float* __restrict__ c2w,
    short* __restrict__ wsw, float* __restrict__ tbg)
{
  int tid = threadIdx.x;
  if (blockIdx.x < 288) {
    int e0 = (blockIdx.x * 256 + tid) * 4;
#pragma unroll
    for (int i = 0; i < 4; ++i) {
      int e = e0 + i;
      float v;
      if (e < 16384) v = vw[e];
      else if (e < 32768) v = ow[e - 16384];
      else if (e < 98304) v = iw[e - 32768];
      else if (e < 163840) v = fw[e - 98304];
      else v = dw[e - 163840];
      wsw[e] = f2bf(v);
    }
    return;
  }
  // CPB table: row handled by 8 threads, each 64 j-iterations
  int bb = blockIdx.x - 288;          // 0..7
  int row = bb * 32 + (tid >> 3);     // 0..255
  int k = tid & 7;
  if (row < 225) {
    float t0 = tbl[row * 2 + 0], t1 = tbl[row * 2 + 1];
    float s0 = 0.f, s1 = 0.f, s2 = 0.f, s3 = 0.f;
    int j0 = k * 64;
    for (int j = j0; j < j0 + 64; ++j) {
      float hv = fmaxf(t0 * c0w[j * 2] + t1 * c0w[j * 2 + 1] + c0b[j], 0.f);
      s0 += hv * c2w[j];
      s1 += hv * c2w[512 + j];
      s2 += hv * c2w[1024 + j];
      s3 += hv * c2w[1536 + j];
    }
    s0 += __shfl_xor(s0, 1); s0 += __shfl_xor(s0, 2); s0 += __shfl_xor(s0, 4);
    s1 += __shfl_xor(s1, 1); s1 += __shfl_xor(s1, 2); s1 += __shfl_xor(s1, 4);
    s2 += __shfl_xor(s2, 1); s2 += __shfl_xor(s2, 2); s2 += __shfl_xor(s2, 4);
    s3 += __shfl_xor(s3, 1); s3 += __shfl_xor(s3, 2); s3 += __shfl_xor(s3, 4);
    if (k == 0) {
      tbg[row * 4 + 0] = s0; tbg[row * 4 + 1] = s1;
      tbg[row * 4 + 2] = s2; tbg[row * 4 + 3] = s3;
    }
  }
}

// ---------------------------------------------------------------- k_bias
// 16 blocks x 1024 entries: bias[h][q][k] = 16*sigmoid(tb[idx][h])
__global__ __launch_bounds__(256) void k_bias(
    const float* __restrict__ tbg, const int* __restrict__ rpi,
    float* __restrict__ bias)
{
  __shared__ float tb[900];
  __shared__ int orAcc;
  int tid = threadIdx.x;
  if (tid == 0) orAcc = 0;
  for (int i = tid; i < 900; i += 256) tb[i] = tbg[i];
  __syncthreads();
  int my = 0;
  for (int i = tid; i < 2048; i += 256) my |= rpi[2 * i + 1];
  atomicOr(&orAcc, my);
  __syncthreads();
  bool i64 = (orAcc == 0);
#pragma unroll
  for (int it = 0; it < 4; ++it) {
    int e = blockIdx.x * 1024 + it * 256 + tid;
    int rem = e & 4095;
    int h = e >> 12;
    int idx = i64 ? rpi[2 * rem] : rpi[rem];
    bias[e] = 16.f / (1.f + __expf(-tb[idx * 4 + h]));
  }
}

// ---------------------------------------------------------------- k_attn
// (proven R18 form: P-split 32 KB LDS, launch_bounds(256,3))
__global__ __launch_bounds__(256, 3) void k_attn(
    const float* __restrict__ hswp, const float* __restrict__ qg,
    const float* __restrict__ kg, const float* __restrict__ lsc,
    const float* __restrict__ vb, const short* __restrict__ wvb,
    const float* __restrict__ bias, short* __restrict__ ctx)
{
  __shared__ short lds[16384];
  const int bw = blockIdx.x, tid = threadIdx.x;
  const int lane = tid & 63, h = tid >> 6;
  const int r16 = lane & 15, b4 = lane >> 4;

  const float* qp = qg + ((size_t)bw * 4 + h) * 2048;
  const float* kp = kg + ((size_t)bw * 4 + h) * 2048;
  const float* hp = hswp + (size_t)bw * 8192;

  s8 qf[4], kf[4];
#pragma unroll
  for (int t = 0; t < 4; ++t) qf[t] = nfrag(qp + (t * 16 + r16) * 32 + b4 * 8);
#pragma unroll
  for (int t = 0; t < 4; ++t) kf[t] = nfrag(kp + (t * 16 + r16) * 32 + b4 * 8);

  {
    int row = tid >> 2, c0 = (tid & 3) * 32;
    const float* src = hp + row * 128 + c0;
    short* dst = &lds[row * 136 + c0];
#pragma unroll
    for (int j = 0; j < 4; ++j)
      *(s8*)(dst + j * 8) = cfrag(src + j * 8);
  }
  __syncthreads();

  f4 vac[2][4];
#pragma unroll
  for (int ct = 0; ct < 2; ++ct)
#pragma unroll
    for (int tt = 0; tt < 4; ++tt) vac[ct][tt] = (f4){0.f, 0.f, 0.f, 0.f};
#pragma unroll
  for (int ks = 0; ks < 4; ++ks) {
    s8 bfr[4];
#pragma unroll
    for (int tt = 0; tt < 4; ++tt)
      bfr[tt] = *(const s8*)&lds[(tt * 16 + r16) * 136 + ks * 32 + b4 * 8];
#pragma unroll
    for (int ct = 0; ct < 2; ++ct) {
      s8 af = *(const s8*)(wvb + (size_t)(h * 32 + ct * 16 + r16) * 128 + ks * 32 + b4 * 8);
#pragma unroll
      for (int tt = 0; tt < 4; ++tt)
        vac[ct][tt] = mfma16(af, bfr[tt], vac[ct][tt]);
    }
  }

  f4 sac[4][4];
#pragma unroll
  for (int a = 0; a < 4; ++a)
#pragma unroll
    for (int b = 0; b < 4; ++b) sac[a][b] = (f4){0.f, 0.f, 0.f, 0.f};
#pragma unroll
  for (int kt = 0; kt < 4; ++kt)
#pragma unroll
    for (int qt = 0; qt < 4; ++qt)
      sac[kt][qt] = mfma16(kf[kt], qf[qt], sac[kt][qt]);

  float scal = __expf(fminf(lsc[h], 4.60517019f));
  float rden[4];
#pragma unroll
  for (int qt = 0; qt < 4; ++qt) {
    float m = -1e30f;
#pragma unroll
    for (int kt = 0; kt < 4; ++kt) {
      f4 bv = *(const f4*)(bias + (h * 64 + qt * 16 + r16) * 64 + kt * 16 + b4 * 4);
#pragma unroll
      for (int r = 0; r < 4; ++r) {
        float sv = sac[kt][qt][r] * scal + bv[r];
        sac[kt][qt][r] = sv;
        m = fmaxf(m, sv);
      }
    }
    m = fmaxf(m, __shfl_xor(m, 16));
    m = fmaxf(m, __shfl_xor(m, 32));
    float sum = 0.f;
#pragma unroll
    for (int kt = 0; kt < 4; ++kt)
#pragma unroll
      for (int r = 0; r < 4; ++r) {
        float e = __expf(sac[kt][qt][r] - m);
        sac[kt][qt][r] = e;
        sum += e;
      }
    sum += __shfl_xor(sum, 16);
    sum += __shfl_xor(sum, 32);
    rden[qt] = 1.0f / sum;
  }

  __syncthreads();

  short* Vt = &lds[h * 4096];
  short* Ph = &lds[h * 4096 + 2048];

#pragma unroll
  for (int ct = 0; ct < 2; ++ct)
#pragma unroll
    for (int r = 0; r < 4; ++r) {
      int row = ct * 16 + b4 * 4 + r;
      float bvl = vb[h * 32 + row];
#pragma unroll
      for (int tt = 0; tt < 4; ++tt) {
        int col = tt * 16 + r16;
        Vt[row * 64 + (col ^ SWZ(row))] = f2bf(vac[ct][tt][r] + bvl);
      }
    }

  f4 cac[2][4];
#pragma unroll
  for (int a = 0; a < 2; ++a)
#pragma unroll
    for (int b = 0; b < 4; ++b) cac[a][b] = (f4){0.f, 0.f, 0.f, 0.f};

#pragma unroll
  for (int half = 0; half < 2; ++half) {
#pragma unroll
    for (int qt2 = 0; qt2 < 2; ++qt2) {
      int qt = half * 2 + qt2;
      int ql = qt2 * 16 + r16;
#pragma unroll
      for (int kt = 0; kt < 4; ++kt) {
        s4 p4;
#pragma unroll
        for (int r = 0; r < 4; ++r) p4[r] = f2bf(sac[kt][qt][r] * rden[qt]);
        *(s4*)&Ph[ql * 64 + ((kt * 16 + b4 * 4) ^ SWZ(ql))] = p4;
      }
    }
#pragma unroll
    for (int ks = 0; ks < 2; ++ks) {
      s8 pf[2];
#pragma unroll
      for (int qt2 = 0; qt2 < 2; ++qt2) {
        int ql = qt2 * 16 + r16;
        pf[qt2] = *(const s8*)&Ph[ql * 64 + ((ks * 32 + b4 * 8) ^ SWZ(ql))];
      }
#pragma unroll
      for (int dt = 0; dt < 2; ++dt) {
        int row = dt * 16 + r16;
        s8 vf = *(const s8*)&Vt[row * 64 + ((ks * 32 + b4 * 8) ^ SWZ(row))];
#pragma unroll
        for (int qt2 = 0; qt2 < 2; ++qt2)
          cac[dt][half * 2 + qt2] = mfma16(vf, pf[qt2], cac[dt][half * 2 + qt2]);
      }
    }
  }
#pragma unroll
  for (int qt = 0; qt < 4; ++qt)
#pragma unroll
    for (int dt = 0; dt < 2; ++dt) {
      s4 o;
#pragma unroll
      for (int r = 0; r < 4; ++r) o[r] = f2bf(cac[dt][qt][r]);
      *(s4*)(ctx + (size_t)(bw * 64 + qt * 16 + r16) * 128 + h * 32 + dt * 16 + b4 * 4) = o;
    }
}

// ---------------------------------------------------------------- k_fuse
// R19 form + residual kept in 4 packed s8 regs (VGPR 64->~80, cap 128):
// removes early lo write + final lo read (66 MB of traffic).
__global__ __launch_bounds__(512, 4) void k_fuse(
    const short* __restrict__ ctx, const short* __restrict__ owb,
    const float* __restrict__ ob, const float* __restrict__ emb,
    const float* __restrict__ lnbw, const float* __restrict__ lnbb,
    const short* __restrict__ iwb, const float* __restrict__ ib,
    const short* __restrict__ fwb, const float* __restrict__ fb,
    const float* __restrict__ lnaw, const float* __restrict__ lnab,
    short* __restrict__ lo)
{
  __shared__ short Bs[128 * 136];
  __shared__ short ht[8][2184];
  const int tid = threadIdx.x, lane = tid & 63, wv = tid >> 6;
  const int r16 = lane & 15, b4 = lane >> 4;
  const int obase = blockIdx.x * 128 + wv * 16;

#pragma unroll
  for (int it = 0; it < 4; ++it) {
    int ch = it * 512 + tid, n = ch >> 4, k8 = ch & 15;
    *(s8*)&Bs[n * 136 + k8 * 8] = *(const s8*)(owb + (size_t)n * 128 + k8 * 8);
  }
  __syncthreads();

  int m = obase + r16;
  int bb = m >> 12, rimg = (m >> 6) & 63, cimg = m & 63;
  long tok = ((long)(bb * 64 + (rimg >> 3) * 8 + (cimg >> 3)) << 6)
           + (rimg & 7) * 8 + (cimg & 7);
  const short* ap = ctx + tok * 128;

  f4 acc[8];
#pragma unroll
  for (int nt = 0; nt < 8; ++nt) acc[nt] = (f4){0.f, 0.f, 0.f, 0.f};
#pragma unroll
  for (int ks = 0; ks < 4; ++ks) {
    s8 af = *(const s8*)(ap + ks * 32 + b4 * 8);
#pragma unroll
    for (int nt = 0; nt < 8; ++nt) {
      s8 bf = *(const s8*)&Bs[(nt * 16 + r16) * 136 + ks * 32 + b4 * 8];
      acc[nt] = mfma16(af, bf, acc[nt]);
    }
  }
  s8 hr[4];   // residual hs (bf16) kept in registers
#pragma unroll
  for (int r = 0; r < 4; ++r) {
    int t = b4 * 4 + r;
    long orow = obase + t;
    float x[8];
    float s = 0.f, s2 = 0.f;
#pragma unroll
    for (int nt = 0; nt < 8; ++nt) {
      int c = nt * 16 + r16;
      x[nt] = acc[nt][r] + ob[c];
      s += x[nt]; s2 += x[nt] * x[nt];
    }
    s += __shfl_xor(s, 1); s += __shfl_xor(s, 2); s += __shfl_xor(s, 4); s += __shfl_xor(s, 8);
    s2 += __shfl_xor(s2, 1); s2 += __shfl_xor(s2, 2); s2 += __shfl_xor(s2, 4); s2 += __shfl_xor(s2, 8);
    float mu = s * (1.f / 128.f);
    float var = s2 * (1.f / 128.f) - mu * mu;
    float rs = rsqrtf(var + 1e-5f);
#pragma unroll
    for (int nt = 0; nt < 8; ++nt) {
      int c = nt * 16 + r16;
      float y = (x[nt] - mu) * rs * lnbw[c] + lnbb[c] + emb[orow * 128 + c];
      short yb = f2bf(y);
      ht[wv][t * 136 + c] = yb;
      hr[r][nt] = yb;
    }
  }

  s8 af1[4];
#pragma unroll
  for (int ks = 0; ks < 4; ++ks)
    af1[ks] = *(const s8*)&ht[wv][r16 * 136 + ks * 32 + b4 * 8];

  f4 acc2[8];
#pragma unroll
  for (int nt = 0; nt < 8; ++nt) acc2[nt] = (f4){0.f, 0.f, 0.f, 0.f};

  for (int cc = 0; cc < 4; ++cc) {
    int n0 = cc * 128;
    __syncthreads();
#pragma unroll
    for (int it = 0; it < 4; ++it) {
      int ch = it * 512 + tid, n = ch >> 4, k8 = ch & 15;
      *(s8*)&Bs[n * 136 + k8 * 8] = *(const s8*)(iwb + (size_t)(n0 + n) * 128 + k8 * 8);
    }
    __syncthreads();
    f4 a1[8];
#pragma unroll
    for (int nt = 0; nt < 8; ++nt) a1[nt] = (f4){0.f, 0.f, 0.f, 0.f};
#pragma unroll
    for (int ks = 0; ks < 4; ++ks) {
#pragma unroll
      for (int nt = 0; nt < 8; ++nt) {
        s8 bf = *(const s8*)&Bs[(nt * 16 + r16) * 136 + ks * 32 + b4 * 8];
        a1[nt] = mfma16(af1[ks], bf, a1[nt]);
      }
    }
#pragma unroll
    for (int r = 0; r < 4; ++r) {
      int t = b4 * 4 + r;
#pragma unroll
      for (int nt = 0; nt < 8; ++nt) {
        int c = nt * 16 + r16;
        float xg = a1[nt][r] + ib[n0 + c];
        float g = 0.5f * xg * (1.0f + erff(xg * 0.70710678118f));
        ht[wv][t * 136 + c] = f2bf(g);
      }
    }
    __syncthreads();
#pragma unroll
    for (int it = 0; it < 4; ++it) {
      int ch = it * 512 + tid, n = ch >> 4, k8 = ch & 15;
      *(s8*)&Bs[n * 136 + k8 * 8] = *(const s8*)(fwb + (size_t)n * 512 + n0 + k8 * 8);
    }
    __syncthreads();
#pragma unroll
    for (int ks = 0; ks < 4; ++ks) {
      s8 af2 = *(const s8*)&ht[wv][r16 * 136 + ks * 32 + b4 * 8];
#pragma unroll
      for (int nt = 0; nt < 8; ++nt) {
        s8 bf = *(const s8*)&Bs[(nt * 16 + r16) * 136 + ks * 32 + b4 * 8];
        acc2[nt] = mfma16(af2, bf, acc2[nt]);
      }
    }
  }

#pragma unroll
  for (int r = 0; r < 4; ++r) {
    int t = b4 * 4 + r;
    long orow = obase + t;
    float x[8];
    float s = 0.f, s2 = 0.f;
#pragma unroll
    for (int nt = 0; nt < 8; ++nt) {
      int c = nt * 16 + r16;
      x[nt] = acc2[nt][r] + fb[c];
      s += x[nt]; s2 += x[nt] * x[nt];
    }
    s += __shfl_xor(s, 1); s += __shfl_xor(s, 2); s += __shfl_xor(s, 4); s += __shfl_xor(s, 8);
    s2 += __shfl_xor(s2, 1); s2 += __shfl_xor(s2, 2); s2 += __shfl_xor(s2, 4); s2 += __shfl_xor(s2, 8);
    float mu = s * (1.f / 128.f);
    float var = s2 * (1.f / 128.f) - mu * mu;
    float rs = rsqrtf(var + 1e-5f);
#pragma unroll
    for (int nt = 0; nt < 8; ++nt) {
      int c = nt * 16 + r16;
      float y = (x[nt] - mu) * rs * lnaw[c] + lnab[c] + bf2f(hr[r][nt]);
      lo[orow * 128 + c] = f2bf(y);
    }
  }
}

// ---------------------------------------------------------------- k_merge
__global__ __launch_bounds__(512) void k_merge(
    const short* __restrict__ lo, const short* __restrict__ dwb,
    const float* __restrict__ dsw, const float* __restrict__ dsb,
    float* __restrict__ out)
{
  __shared__ short Bs[256 * 136];
  const int tid = threadIdx.x;
  const int lane = tid & 63, wv = tid >> 6, r16 = lane & 15, b4 = lane >> 4;
  const int mrow = blockIdx.x * 128 + wv * 16;
  f4 acc[16];
#pragma unroll
  for (int nt = 0; nt < 16; ++nt) acc[nt] = (f4){0.f, 0.f, 0.f, 0.f};
  for (int kc = 0; kc < 4; ++kc) {
    if (kc) __syncthreads();
#pragma unroll
    for (int it = 0; it < 8; ++it) {
      int ch = it * 512 + tid, n = ch >> 4, k8 = ch & 15;
      *(s8*)&Bs[n * 136 + k8 * 8] = *(const s8*)(dwb + (size_t)n * 512 + kc * 128 + k8 * 8);
    }
    __syncthreads();
    int m = mrow + r16;
    int bb = m >> 10, p = m & 1023, ii = p >> 5, jj = p & 31;
    long row = (long)bb * 4096 + (2 * ii + (kc & 1)) * 64 + (2 * jj + (kc >> 1));
    const short* ap = lo + row * 128;
#pragma unroll
    for (int ks = 0; ks < 4; ++ks) {
      s8 af = *(const s8*)(ap + ks * 32 + b4 * 8);
#pragma unroll
      for (int nt = 0; nt < 16; ++nt) {
        s8 bf = *(const s8*)&Bs[(nt * 16 + r16) * 136 + ks * 32 + b4 * 8];
        acc[nt] = mfma16(af, bf, acc[nt]);
      }
    }
  }
#pragma unroll
  for (int r = 0; r < 4; ++r) {
    size_t m = mrow + b4 * 4 + r;
    float x[16];
    float s = 0.f, s2 = 0.f;
#pragma unroll
    for (int nt = 0; nt < 16; ++nt) {
      x[nt] = acc[nt][r];
      s += x[nt]; s2 += x[nt] * x[nt];
    }
    s += __shfl_xor(s, 1); s += __shfl_xor(s, 2); s += __shfl_xor(s, 4); s += __shfl_xor(s, 8);
    s2 += __shfl_xor(s2, 1); s2 += __shfl_xor(s2, 2); s2 += __shfl_xor(s2, 4); s2 += __shfl_xor(s2, 8);
    float mu = s * (1.f / 256.f);
    float var = s2 * (1.f / 256.f) - mu * mu;
    float rs = rsqrtf(var + 1e-5f);
#pragma unroll
    for (int nt = 0; nt < 16; ++nt) {
      int c = nt * 16 + r16;
      out[m * 256 + c] = (x[nt] - mu) * rs * dsw[c] + dsb[c];
    }
  }
}

// ---------------------------------------------------------------- launch
extern "C" void kernel_launch(void* const* d_in, const int* in_sizes, int n_in,
                              void* d_out, int out_size, void* d_ws, size_t ws_size,
                              hipStream_t stream)
{
  const float* out_dense_b = (const float*)d_in[0];
  const float* out_dense_w = (const float*)d_in[1];
  const float* rel_tbl     = (const float*)d_in[2];
  const float* cpb0_b      = (const float*)d_in[3];
  const float* cpb0_w      = (const float*)d_in[4];
  const float* cpb2_w      = (const float*)d_in[5];
  const float* value_b     = (const float*)d_in[6];
  const float* value_w     = (const float*)d_in[7];
  const float* logit_scale = (const float*)d_in[8];
  const float* inter_b     = (const float*)d_in[9];
  const float* inter_w     = (const float*)d_in[10];
  const float* ln_after_b  = (const float*)d_in[11];
  const float* ln_after_w  = (const float*)d_in[12];
  const float* ln_before_b = (const float*)d_in[13];
  const float* ln_before_w = (const float*)d_in[14];
  const float* ffn_out_b   = (const float*)d_in[15];
  const float* ffn_out_w   = (const float*)d_in[16];
  const float* ds_norm_b   = (const float*)d_in[17];
  const float* ds_norm_w   = (const float*)d_in[18];
  const float* ds_red_w    = (const float*)d_in[19];
  const float* emb         = (const float*)d_in[20];
  const float* hsw         = (const float*)d_in[21];
  const float* keyl        = (const float*)d_in[22];
  const float* queryl      = (const float*)d_in[23];
  const int*   rpi         = (const int*)d_in[24];

  char* ws = (char*)d_ws;
  short* wsw  = (short*)ws;                                  // 589824 B
  float* bias = (float*)(ws + 589824);                       // 65536 B
  float* tbg  = (float*)(ws + 655360);                       // 4096 B
  short* ctx  = (short*)(ws + 659456);                       // 33554432 B
  short* lo   = (short*)(ws + 659456 + 33554432ULL);         // 33554432 B

  short* wv_bf = wsw;
  short* ow_bf = wsw + 16384;
  short* iw_bf = wsw + 32768;
  short* fw_bf = wsw + 98304;
  short* dw_bf = wsw + 163840;

  k_prep<<<296, 256, 0, stream>>>(value_w, out_dense_w, inter_w, ffn_out_w, ds_red_w,
                                  rel_tbl, cpb0_b, cpb0_w, cpb2_w, wsw, tbg);
  k_bias<<<16, 256, 0, stream>>>(tbg, rpi, bias);
  k_attn<<<2048, 256, 0, stream>>>(hsw, queryl, keyl, logit_scale, value_b, wv_bf, bias, ctx);
  k_fuse<<<1024, 512, 0, stream>>>(ctx, ow_bf, out_dense_b, emb, ln_before_w, ln_before_b,
                                   iw_bf, inter_b, fw_bf, ffn_out_b,
                                   ln_after_w, ln_after_b, lo);
  k_merge<<<256, 512, 0, stream>>>(lo, dw_bf, ds_norm_w, ds_norm_b, (float*)d_out);
}

// Round 21
// 232.709 us; speedup vs baseline: 1.0872x; 1.0872x over previous
//
#include <hip/hip_runtime.h>
#include <hip/hip_bf16.h>

typedef __attribute__((ext_vector_type(4))) float f4;
typedef __attribute__((ext_vector_type(8))) short s8;
typedef __attribute__((ext_vector_type(4))) short s4;

__device__ __forceinline__ short f2bf(float f){
  __hip_bfloat16 h = __float2bfloat16(f);
  return __builtin_bit_cast(short, h);
}
__device__ __forceinline__ float bf2f(short h){
  unsigned u = ((unsigned)(unsigned short)h) << 16;
  return __builtin_bit_cast(float, u);
}
__device__ __forceinline__ f4 mfma16(s8 a, s8 b, f4 c){
  return __builtin_amdgcn_mfma_f32_16x16x32_bf16(a, b, c, 0, 0, 0);
}
__device__ __forceinline__ s8 cfrag(const float* p){
  f4 a = *(const f4*)p; f4 b = *(const f4*)(p + 4);
  s8 t = {f2bf(a[0]), f2bf(a[1]), f2bf(a[2]), f2bf(a[3]),
          f2bf(b[0]), f2bf(b[1]), f2bf(b[2]), f2bf(b[3])};
  return t;
}
__device__ __forceinline__ s8 nfrag(const float* p){
  f4 a = *(const f4*)p; f4 b = *(const f4*)(p + 4);
  float ss = a[0]*a[0]+a[1]*a[1]+a[2]*a[2]+a[3]*a[3]
           + b[0]*b[0]+b[1]*b[1]+b[2]*b[2]+b[3]*b[3];
  ss += __shfl_xor(ss, 16); ss += __shfl_xor(ss, 32);
  float f = 1.0f / fmaxf(sqrtf(ss), 1e-12f);
  s8 t = {f2bf(a[0]*f), f2bf(a[1]*f), f2bf(a[2]*f), f2bf(a[3]*f),
          f2bf(b[0]*f), f2bf(b[1]*f), f2bf(b[2]*f), f2bf(b[3]*f)};
  return t;
}
#define SWZ(row) ((((row) ^ ((row) >> 3)) & 7) << 3)

// ---------------------------------------------------------------- k_prep
// blocks 0..287: weight f32->bf16 conversion.
// blocks 288..295: CPB MLP table (tbg[900]) — 32 rows/block, 8 thr/row.
__global__ __launch_bounds__(256) void k_prep(
    const float* __restrict__ vw, const float* __restrict__ ow,
    const float* __restrict__ iw, const float* __restrict__ fw,
    const float* __restrict__ dw, const float* __restrict__ tbl,
    const float* __restrict__ c0b, const float* __restrict__ c0w,
    const float* __restrict__ c2w,
    short* __restrict__ wsw, float* __restrict__ tbg)
{
  int tid = threadIdx.x;
  if (blockIdx.x < 288) {
    int e0 = (blockIdx.x * 256 + tid) * 4;
#pragma unroll
    for (int i = 0; i < 4; ++i) {
      int e = e0 + i;
      float v;
      if (e < 16384) v = vw[e];
      else if (e < 32768) v = ow[e - 16384];
      else if (e < 98304) v = iw[e - 32768];
      else if (e < 163840) v = fw[e - 98304];
      else v = dw[e - 163840];
      wsw[e] = f2bf(v);
    }
    return;
  }
  int bb = blockIdx.x - 288;
  int row = bb * 32 + (tid >> 3);
  int k = tid & 7;
  if (row < 225) {
    float t0 = tbl[row * 2 + 0], t1 = tbl[row * 2 + 1];
    float s0 = 0.f, s1 = 0.f, s2 = 0.f, s3 = 0.f;
    int j0 = k * 64;
    for (int j = j0; j < j0 + 64; ++j) {
      float hv = fmaxf(t0 * c0w[j * 2] + t1 * c0w[j * 2 + 1] + c0b[j], 0.f);
      s0 += hv * c2w[j];
      s1 += hv * c2w[512 + j];
      s2 += hv * c2w[1024 + j];
      s3 += hv * c2w[1536 + j];
    }
    s0 += __shfl_xor(s0, 1); s0 += __shfl_xor(s0, 2); s0 += __shfl_xor(s0, 4);
    s1 += __shfl_xor(s1, 1); s1 += __shfl_xor(s1, 2); s1 += __shfl_xor(s1, 4);
    s2 += __shfl_xor(s2, 1); s2 += __shfl_xor(s2, 2); s2 += __shfl_xor(s2, 4);
    s3 += __shfl_xor(s3, 1); s3 += __shfl_xor(s3, 2); s3 += __shfl_xor(s3, 4);
    if (k == 0) {
      tbg[row * 4 + 0] = s0; tbg[row * 4 + 1] = s1;
      tbg[row * 4 + 2] = s2; tbg[row * 4 + 3] = s3;
    }
  }
}

// ---------------------------------------------------------------- k_bias
__global__ __launch_bounds__(256) void k_bias(
    const float* __restrict__ tbg, const int* __restrict__ rpi,
    float* __restrict__ bias)
{
  __shared__ float tb[900];
  __shared__ int orAcc;
  int tid = threadIdx.x;
  if (tid == 0) orAcc = 0;
  for (int i = tid; i < 900; i += 256) tb[i] = tbg[i];
  __syncthreads();
  int my = 0;
  for (int i = tid; i < 2048; i += 256) my |= rpi[2 * i + 1];
  atomicOr(&orAcc, my);
  __syncthreads();
  bool i64 = (orAcc == 0);
#pragma unroll
  for (int it = 0; it < 4; ++it) {
    int e = blockIdx.x * 1024 + it * 256 + tid;
    int rem = e & 4095;
    int h = e >> 12;
    int idx = i64 ? rpi[2 * rem] : rpi[rem];
    bias[e] = 16.f / (1.f + __expf(-tb[idx * 4 + h]));
  }
}

// ---------------------------------------------------------------- k_attn
// (proven R18 form: P-split 32 KB LDS, launch_bounds(256,3))
__global__ __launch_bounds__(256, 3) void k_attn(
    const float* __restrict__ hswp, const float* __restrict__ qg,
    const float* __restrict__ kg, const float* __restrict__ lsc,
    const float* __restrict__ vb, const short* __restrict__ wvb,
    const float* __restrict__ bias, short* __restrict__ ctx)
{
  __shared__ short lds[16384];
  const int bw = blockIdx.x, tid = threadIdx.x;
  const int lane = tid & 63, h = tid >> 6;
  const int r16 = lane & 15, b4 = lane >> 4;

  const float* qp = qg + ((size_t)bw * 4 + h) * 2048;
  const float* kp = kg + ((size_t)bw * 4 + h) * 2048;
  const float* hp = hswp + (size_t)bw * 8192;

  s8 qf[4], kf[4];
#pragma unroll
  for (int t = 0; t < 4; ++t) qf[t] = nfrag(qp + (t * 16 + r16) * 32 + b4 * 8);
#pragma unroll
  for (int t = 0; t < 4; ++t) kf[t] = nfrag(kp + (t * 16 + r16) * 32 + b4 * 8);

  {
    int row = tid >> 2, c0 = (tid & 3) * 32;
    const float* src = hp + row * 128 + c0;
    short* dst = &lds[row * 136 + c0];
#pragma unroll
    for (int j = 0; j < 4; ++j)
      *(s8*)(dst + j * 8) = cfrag(src + j * 8);
  }
  __syncthreads();

  f4 vac[2][4];
#pragma unroll
  for (int ct = 0; ct < 2; ++ct)
#pragma unroll
    for (int tt = 0; tt < 4; ++tt) vac[ct][tt] = (f4){0.f, 0.f, 0.f, 0.f};
#pragma unroll
  for (int ks = 0; ks < 4; ++ks) {
    s8 bfr[4];
#pragma unroll
    for (int tt = 0; tt < 4; ++tt)
      bfr[tt] = *(const s8*)&lds[(tt * 16 + r16) * 136 + ks * 32 + b4 * 8];
#pragma unroll
    for (int ct = 0; ct < 2; ++ct) {
      s8 af = *(const s8*)(wvb + (size_t)(h * 32 + ct * 16 + r16) * 128 + ks * 32 + b4 * 8);
#pragma unroll
      for (int tt = 0; tt < 4; ++tt)
        vac[ct][tt] = mfma16(af, bfr[tt], vac[ct][tt]);
    }
  }

  f4 sac[4][4];
#pragma unroll
  for (int a = 0; a < 4; ++a)
#pragma unroll
    for (int b = 0; b < 4; ++b) sac[a][b] = (f4){0.f, 0.f, 0.f, 0.f};
#pragma unroll
  for (int kt = 0; kt < 4; ++kt)
#pragma unroll
    for (int qt = 0; qt < 4; ++qt)
      sac[kt][qt] = mfma16(kf[kt], qf[qt], sac[kt][qt]);

  float scal = __expf(fminf(lsc[h], 4.60517019f));
  float rden[4];
#pragma unroll
  for (int qt = 0; qt < 4; ++qt) {
    float m = -1e30f;
#pragma unroll
    for (int kt = 0; kt < 4; ++kt) {
      f4 bv = *(const f4*)(bias + (h * 64 + qt * 16 + r16) * 64 + kt * 16 + b4 * 4);
#pragma unroll
      for (int r = 0; r < 4; ++r) {
        float sv = sac[kt][qt][r] * scal + bv[r];
        sac[kt][qt][r] = sv;
        m = fmaxf(m, sv);
      }
    }
    m = fmaxf(m, __shfl_xor(m, 16));
    m = fmaxf(m, __shfl_xor(m, 32));
    float sum = 0.f;
#pragma unroll
    for (int kt = 0; kt < 4; ++kt)
#pragma unroll
      for (int r = 0; r < 4; ++r) {
        float e = __expf(sac[kt][qt][r] - m);
        sac[kt][qt][r] = e;
        sum += e;
      }
    sum += __shfl_xor(sum, 16);
    sum += __shfl_xor(sum, 32);
    rden[qt] = 1.0f / sum;
  }

  __syncthreads();

  short* Vt = &lds[h * 4096];
  short* Ph = &lds[h * 4096 + 2048];

#pragma unroll
  for (int ct = 0; ct < 2; ++ct)
#pragma unroll
    for (int r = 0; r < 4; ++r) {
      int row = ct * 16 + b4 * 4 + r;
      float bvl = vb[h * 32 + row];
#pragma unroll
      for (int tt = 0; tt < 4; ++tt) {
        int col = tt * 16 + r16;
        Vt[row * 64 + (col ^ SWZ(row))] = f2bf(vac[ct][tt][r] + bvl);
      }
    }

  f4 cac[2][4];
#pragma unroll
  for (int a = 0; a < 2; ++a)
#pragma unroll
    for (int b = 0; b < 4; ++b) cac[a][b] = (f4){0.f, 0.f, 0.f, 0.f};

#pragma unroll
  for (int half = 0; half < 2; ++half) {
#pragma unroll
    for (int qt2 = 0; qt2 < 2; ++qt2) {
      int qt = half * 2 + qt2;
      int ql = qt2 * 16 + r16;
#pragma unroll
      for (int kt = 0; kt < 4; ++kt) {
        s4 p4;
#pragma unroll
        for (int r = 0; r < 4; ++r) p4[r] = f2bf(sac[kt][qt][r] * rden[qt]);
        *(s4*)&Ph[ql * 64 + ((kt * 16 + b4 * 4) ^ SWZ(ql))] = p4;
      }
    }
#pragma unroll
    for (int ks = 0; ks < 2; ++ks) {
      s8 pf[2];
#pragma unroll
      for (int qt2 = 0; qt2 < 2; ++qt2) {
        int ql = qt2 * 16 + r16;
        pf[qt2] = *(const s8*)&Ph[ql * 64 + ((ks * 32 + b4 * 8) ^ SWZ(ql))];
      }
#pragma unroll
      for (int dt = 0; dt < 2; ++dt) {
        int row = dt * 16 + r16;
        s8 vf = *(const s8*)&Vt[row * 64 + ((ks * 32 + b4 * 8) ^ SWZ(row))];
#pragma unroll
        for (int qt2 = 0; qt2 < 2; ++qt2)
          cac[dt][half * 2 + qt2] = mfma16(vf, pf[qt2], cac[dt][half * 2 + qt2]);
      }
    }
  }
#pragma unroll
  for (int qt = 0; qt < 4; ++qt)
#pragma unroll
    for (int dt = 0; dt < 2; ++dt) {
      s4 o;
#pragma unroll
      for (int r = 0; r < 4; ++r) o[r] = f2bf(cac[dt][qt][r]);
      *(s4*)(ctx + (size_t)(bw * 64 + qt * 16 + r16) * 128 + h * 32 + dt * 16 + b4 * 4) = o;
    }
}

// ---------------------------------------------------------------- k_fuse
// EXACT R19 form (proven ~119 us): 512 thr / 8 waves / M=128, erff GELU,
// residual via lo round-trip (register/array residual spills — 3x proven).
__global__ __launch_bounds__(512, 4) void k_fuse(
    const short* __restrict__ ctx, const short* __restrict__ owb,
    const float* __restrict__ ob, const float* __restrict__ emb,
    const float* __restrict__ lnbw, const float* __restrict__ lnbb,
    const short* __restrict__ iwb, const float* __restrict__ ib,
    const short* __restrict__ fwb, const float* __restrict__ fb,
    const float* __restrict__ lnaw, const float* __restrict__ lnab,
    short* __restrict__ lo)
{
  __shared__ short Bs[128 * 136];
  __shared__ short ht[8][2184];
  const int tid = threadIdx.x, lane = tid & 63, wv = tid >> 6;
  const int r16 = lane & 15, b4 = lane >> 4;
  const int obase = blockIdx.x * 128 + wv * 16;

#pragma unroll
  for (int it = 0; it < 4; ++it) {
    int ch = it * 512 + tid, n = ch >> 4, k8 = ch & 15;
    *(s8*)&Bs[n * 136 + k8 * 8] = *(const s8*)(owb + (size_t)n * 128 + k8 * 8);
  }
  __syncthreads();

  int m = obase + r16;
  int bb = m >> 12, rimg = (m >> 6) & 63, cimg = m & 63;
  long tok = ((long)(bb * 64 + (rimg >> 3) * 8 + (cimg >> 3)) << 6)
           + (rimg & 7) * 8 + (cimg & 7);
  const short* ap = ctx + tok * 128;

  f4 acc[8];
#pragma unroll
  for (int nt = 0; nt < 8; ++nt) acc[nt] = (f4){0.f, 0.f, 0.f, 0.f};
#pragma unroll
  for (int ks = 0; ks < 4; ++ks) {
    s8 af = *(const s8*)(ap + ks * 32 + b4 * 8);
#pragma unroll
    for (int nt = 0; nt < 8; ++nt) {
      s8 bf = *(const s8*)&Bs[(nt * 16 + r16) * 136 + ks * 32 + b4 * 8];
      acc[nt] = mfma16(af, bf, acc[nt]);
    }
  }
#pragma unroll
  for (int r = 0; r < 4; ++r) {
    int t = b4 * 4 + r;
    long orow = obase + t;
    float x[8];
    float s = 0.f, s2 = 0.f;
#pragma unroll
    for (int nt = 0; nt < 8; ++nt) {
      int c = nt * 16 + r16;
      x[nt] = acc[nt][r] + ob[c];
      s += x[nt]; s2 += x[nt] * x[nt];
    }
    s += __shfl_xor(s, 1); s += __shfl_xor(s, 2); s += __shfl_xor(s, 4); s += __shfl_xor(s, 8);
    s2 += __shfl_xor(s2, 1); s2 += __shfl_xor(s2, 2); s2 += __shfl_xor(s2, 4); s2 += __shfl_xor(s2, 8);
    float mu = s * (1.f / 128.f);
    float var = s2 * (1.f / 128.f) - mu * mu;
    float rs = rsqrtf(var + 1e-5f);
#pragma unroll
    for (int nt = 0; nt < 8; ++nt) {
      int c = nt * 16 + r16;
      float y = (x[nt] - mu) * rs * lnbw[c] + lnbb[c] + emb[orow * 128 + c];
      short yb = f2bf(y);
      ht[wv][t * 136 + c] = yb;
      lo[orow * 128 + c] = yb;
    }
  }

  s8 af1[4];
#pragma unroll
  for (int ks = 0; ks < 4; ++ks)
    af1[ks] = *(const s8*)&ht[wv][r16 * 136 + ks * 32 + b4 * 8];

  f4 acc2[8];
#pragma unroll
  for (int nt = 0; nt < 8; ++nt) acc2[nt] = (f4){0.f, 0.f, 0.f, 0.f};

  for (int cc = 0; cc < 4; ++cc) {
    int n0 = cc * 128;
    __syncthreads();
#pragma unroll
    for (int it = 0; it < 4; ++it) {
      int ch = it * 512 + tid, n = ch >> 4, k8 = ch & 15;
      *(s8*)&Bs[n * 136 + k8 * 8] = *(const s8*)(iwb + (size_t)(n0 + n) * 128 + k8 * 8);
    }
    __syncthreads();
    f4 a1[8];
#pragma unroll
    for (int nt = 0; nt < 8; ++nt) a1[nt] = (f4){0.f, 0.f, 0.f, 0.f};
#pragma unroll
    for (int ks = 0; ks < 4; ++ks) {
#pragma unroll
      for (int nt = 0; nt < 8; ++nt) {
        s8 bf = *(const s8*)&Bs[(nt * 16 + r16) * 136 + ks * 32 + b4 * 8];
        a1[nt] = mfma16(af1[ks], bf, a1[nt]);
      }
    }
#pragma unroll
    for (int r = 0; r < 4; ++r) {
      int t = b4 * 4 + r;
#pragma unroll
      for (int nt = 0; nt < 8; ++nt) {
        int c = nt * 16 + r16;
        float xg = a1[nt][r] + ib[n0 + c];
        float g = 0.5f * xg * (1.0f + erff(xg * 0.70710678118f));
        ht[wv][t * 136 + c] = f2bf(g);
      }
    }
    __syncthreads();
#pragma unroll
    for (int it = 0; it < 4; ++it) {
      int ch = it * 512 + tid, n = ch >> 4, k8 = ch & 15;
      *(s8*)&Bs[n * 136 + k8 * 8] = *(const s8*)(fwb + (size_t)n * 512 + n0 + k8 * 8);
    }
    __syncthreads();
#pragma unroll
    for (int ks = 0; ks < 4; ++ks) {
      s8 af2 = *(const s8*)&ht[wv][r16 * 136 + ks * 32 + b4 * 8];
#pragma unroll
      for (int nt = 0; nt < 8; ++nt) {
        s8 bf = *(const s8*)&Bs[(nt * 16 + r16) * 136 + ks * 32 + b4 * 8];
        acc2[nt] = mfma16(af2, bf, acc2[nt]);
      }
    }
  }

#pragma unroll
  for (int r = 0; r < 4; ++r) {
    int t = b4 * 4 + r;
    long orow = obase + t;
    float x[8], res[8];
    float s = 0.f, s2 = 0.f;
#pragma unroll
    for (int nt = 0; nt < 8; ++nt) {
      int c = nt * 16 + r16;
      res[nt] = bf2f(lo[orow * 128 + c]);
      x[nt] = acc2[nt][r] + fb[c];
      s += x[nt]; s2 += x[nt] * x[nt];
    }
    s += __shfl_xor(s, 1); s += __shfl_xor(s, 2); s += __shfl_xor(s, 4); s += __shfl_xor(s, 8);
    s2 += __shfl_xor(s2, 1); s2 += __shfl_xor(s2, 2); s2 += __shfl_xor(s2, 4); s2 += __shfl_xor(s2, 8);
    float mu = s * (1.f / 128.f);
    float var = s2 * (1.f / 128.f) - mu * mu;
    float rs = rsqrtf(var + 1e-5f);
#pragma unroll
    for (int nt = 0; nt < 8; ++nt) {
      int c = nt * 16 + r16;
      float y = (x[nt] - mu) * rs * lnaw[c] + lnab[c] + res[nt];
      lo[orow * 128 + c] = f2bf(y);
    }
  }
}

// ---------------------------------------------------------------- k_merge
__global__ __launch_bounds__(512) void k_merge(
    const short* __restrict__ lo, const short* __restrict__ dwb,
    const float* __restrict__ dsw, const float* __restrict__ dsb,
    float* __restrict__ out)
{
  __shared__ short Bs[256 * 136];
  const int tid = threadIdx.x;
  const int lane = tid & 63, wv = tid >> 6, r16 = lane & 15, b4 = lane >> 4;
  const int mrow = blockIdx.x * 128 + wv * 16;
  f4 acc[16];
#pragma unroll
  for (int nt = 0; nt < 16; ++nt) acc[nt] = (f4){0.f, 0.f, 0.f, 0.f};
  for (int kc = 0; kc < 4; ++kc) {
    if (kc) __syncthreads();
#pragma unroll
    for (int it = 0; it < 8; ++it) {
      int ch = it * 512 + tid, n = ch >> 4, k8 = ch & 15;
      *(s8*)&Bs[n * 136 + k8 * 8] = *(const s8*)(dwb + (size_t)n * 512 + kc * 128 + k8 * 8);
    }
    __syncthreads();
    int m = mrow + r16;
    int bb = m >> 10, p = m & 1023, ii = p >> 5, jj = p & 31;
    long row = (long)bb * 4096 + (2 * ii + (kc & 1)) * 64 + (2 * jj + (kc >> 1));
    const short* ap = lo + row * 128;
#pragma unroll
    for (int ks = 0; ks < 4; ++ks) {
      s8 af = *(const s8*)(ap + ks * 32 + b4 * 8);
#pragma unroll
      for (int nt = 0; nt < 16; ++nt) {
        s8 bf = *(const s8*)&Bs[(nt * 16 + r16) * 136 + ks * 32 + b4 * 8];
        acc[nt] = mfma16(af, bf, acc[nt]);
      }
    }
  }
#pragma unroll
  for (int r = 0; r < 4; ++r) {
    size_t m = mrow + b4 * 4 + r;
    float x[16];
    float s = 0.f, s2 = 0.f;
#pragma unroll
    for (int nt = 0; nt < 16; ++nt) {
      x[nt] = acc[nt][r];
      s += x[nt]; s2 += x[nt] * x[nt];
    }
    s += __shfl_xor(s, 1); s += __shfl_xor(s, 2); s += __shfl_xor(s, 4); s += __shfl_xor(s, 8);
    s2 += __shfl_xor(s2, 1); s2 += __shfl_xor(s2, 2); s2 += __shfl_xor(s2, 4); s2 += __shfl_xor(s2, 8);
    float mu = s * (1.f / 256.f);
    float var = s2 * (1.f / 256.f) - mu * mu;
    float rs = rsqrtf(var + 1e-5f);
#pragma unroll
    for (int nt = 0; nt < 16; ++nt) {
      int c = nt * 16 + r16;
      out[m * 256 + c] = (x[nt] - mu) * rs * dsw[c] + dsb[c];
    }
  }
}

// ---------------------------------------------------------------- launch
extern "C" void kernel_launch(void* const* d_in, const int* in_sizes, int n_in,
                              void* d_out, int out_size, void* d_ws, size_t ws_size,
                              hipStream_t stream)
{
  const float* out_dense_b = (const float*)d_in[0];
  const float* out_dense_w = (const float*)d_in[1];
  const float* rel_tbl     = (const float*)d_in[2];
  const float* cpb0_b      = (const float*)d_in[3];
  const float* cpb0_w      = (const float*)d_in[4];
  const float* cpb2_w      = (const float*)d_in[5];
  const float* value_b     = (const float*)d_in[6];
  const float* value_w     = (const float*)d_in[7];
  const float* logit_scale = (const float*)d_in[8];
  const float* inter_b     = (const float*)d_in[9];
  const float* inter_w     = (const float*)d_in[10];
  const float* ln_after_b  = (const float*)d_in[11];
  const float* ln_after_w  = (const float*)d_in[12];
  const float* ln_before_b = (const float*)d_in[13];
  const float* ln_before_w = (const float*)d_in[14];
  const float* ffn_out_b   = (const float*)d_in[15];
  const float* ffn_out_w   = (const float*)d_in[16];
  const float* ds_norm_b   = (const float*)d_in[17];
  const float* ds_norm_w   = (const float*)d_in[18];
  const float* ds_red_w    = (const float*)d_in[19];
  const float* emb         = (const float*)d_in[20];
  const float* hsw         = (const float*)d_in[21];
  const float* keyl        = (const float*)d_in[22];
  const float* queryl      = (const float*)d_in[23];
  const int*   rpi         = (const int*)d_in[24];

  char* ws = (char*)d_ws;
  short* wsw  = (short*)ws;                                  // 589824 B
  float* bias = (float*)(ws + 589824);                       // 65536 B
  float* tbg  = (float*)(ws + 655360);                       // 4096 B
  short* ctx  = (short*)(ws + 659456);                       // 33554432 B
  short* lo   = (short*)(ws + 659456 + 33554432ULL);         // 33554432 B

  short* wv_bf = wsw;
  short* ow_bf = wsw + 16384;
  short* iw_bf = wsw + 32768;
  short* fw_bf = wsw + 98304;
  short* dw_bf = wsw + 163840;

  k_prep<<<296, 256, 0, stream>>>(value_w, out_dense_w, inter_w, ffn_out_w, ds_red_w,
                                  rel_tbl, cpb0_b, cpb0_w, cpb2_w, wsw, tbg);
  k_bias<<<16, 256, 0, stream>>>(tbg, rpi, bias);
  k_attn<<<2048, 256, 0, stream>>>(hsw, queryl, keyl, logit_scale, value_b, wv_bf, bias, ctx);
  k_fuse<<<1024, 512, 0, stream>>>(ctx, ow_bf, out_dense_b, emb, ln_before_w, ln_before_b,
                                   iw_bf, inter_b, fw_bf, ffn_out_b,
                                   ln_after_w, ln_after_b, lo);
  k_merge<<<256, 512, 0, stream>>>(lo, dw_bf, ds_norm_w, ds_norm_b, (float*)d_out);
}